// Round 2
// baseline (273.730 us; speedup 1.0000x reference)
//
#include <hip/hip_runtime.h>
#include <hip/hip_bf16.h>
#include <stdint.h>

// GroupedLinear: y[b, g*256+o] = sum_i x[b, g*256+i] * W[g,o,i] + bias[g,o]
// B=8192, G=16, GIN=GOUT=256. fp32 in/out, bf16 MFMA compute.
//
// 16 independent GEMMs M=8192 N=256 K=256. Memory-bound: ~272 MB HBM floor
// (~43 us @ 6.3 TB/s). fp32 vector compute would be 109 us -> must use MFMA.

#define IN_F   4096
#define OUT_F  4096
#define GIN    256
#define GOUT   256

#define BM 128
#define BN 128
#define BK 64
#define KTOT 256

using short8  = __attribute__((ext_vector_type(8))) short;
using floatx4 = __attribute__((ext_vector_type(4))) float;

// round-to-nearest-even fp32 -> bf16 (branch-free)
__device__ __forceinline__ short f2bf_rne(float f) {
    unsigned u = __builtin_bit_cast(unsigned, f);
    unsigned r = u + 0x7FFFu + ((u >> 16) & 1u);
    return (short)(r >> 16);
}

__global__ __launch_bounds__(256, 2)
void grouped_linear_kernel(const float* __restrict__ X,
                           const float* __restrict__ W,
                           const float* __restrict__ Bias,
                           float* __restrict__ Out) {
    // bf16 LDS tiles, XOR-swizzled in 8-elem (16B) chunks: chunk q of row r
    // stored at q ^ (r&7). Makes both ds_write_b128 and fragment ds_read_b128
    // 2-way bank aliasing (free on gfx950).
    __shared__ __align__(16) short lsA[BM * BK];   // 16 KB
    __shared__ __align__(16) short lsB[BN * BK];   // 16 KB

    const int t    = threadIdx.x;
    const int lane = t & 63;
    const int wave = t >> 6;
    const int wm   = wave >> 1;     // wave row  (0..1) -> 64 rows
    const int wn   = wave & 1;      // wave col  (0..1) -> 64 cols
    const int lrow = lane & 15;
    const int quad = lane >> 4;     // 0..3

    const int bn   = blockIdx.x & 31;   // 32 col-tiles of 128
    const int bm   = blockIdx.x >> 5;   // 64 row-tiles of 128
    const int g    = bn >> 1;           // group (2 col-tiles per group)
    const int row0 = bm * BM;
    const int col0 = bn * BN;
    const int nlb  = (bn & 1) * BN;     // N offset inside this group's W

    const float* Wg = W + (size_t)g * GOUT * GIN + (size_t)nlb * GIN;
    const float* Xg = X + (size_t)row0 * IN_F + g * GIN;

    floatx4 acc[4][4];
    #pragma unroll
    for (int i = 0; i < 4; ++i)
        #pragma unroll
        for (int j = 0; j < 4; ++j)
            acc[i][j] = (floatx4){0.f, 0.f, 0.f, 0.f};

    // staging geometry: 1024 chunks of 8 consecutive floats per tile;
    // 8 threads cover one 64-float row -> fully coalesced 32B/lane reads.
    const int c8 = (t & 7) * 8;     // float offset in the 64-wide K slice
    const int q0 = (t & 7);         // chunk index before swizzle

    for (int kt = 0; kt < KTOT / BK; ++kt) {
        const int kbase = kt * BK;

        // ---- stage A: x fp32 -> bf16 LDS ----
        #pragma unroll
        for (int i = 0; i < 4; ++i) {
            int r = (t >> 3) + 32 * i;                       // 0..127
            const float* src = Xg + (size_t)r * IN_F + kbase + c8;
            floatx4 f0 = *(const floatx4*)src;
            floatx4 f1 = *(const floatx4*)(src + 4);
            short8 p;
            p[0] = f2bf_rne(f0[0]); p[1] = f2bf_rne(f0[1]);
            p[2] = f2bf_rne(f0[2]); p[3] = f2bf_rne(f0[3]);
            p[4] = f2bf_rne(f1[0]); p[5] = f2bf_rne(f1[1]);
            p[6] = f2bf_rne(f1[2]); p[7] = f2bf_rne(f1[3]);
            int q = q0 ^ (r & 7);
            *(short8*)&lsA[r * BK + q * 8] = p;
        }
        // ---- stage B: W fp32 -> bf16 LDS (W[g] is [N][K] row-major) ----
        #pragma unroll
        for (int i = 0; i < 4; ++i) {
            int n = (t >> 3) + 32 * i;                       // 0..127
            const float* src = Wg + (size_t)n * GIN + kbase + c8;
            floatx4 f0 = *(const floatx4*)src;
            floatx4 f1 = *(const floatx4*)(src + 4);
            short8 p;
            p[0] = f2bf_rne(f0[0]); p[1] = f2bf_rne(f0[1]);
            p[2] = f2bf_rne(f0[2]); p[3] = f2bf_rne(f0[3]);
            p[4] = f2bf_rne(f1[0]); p[5] = f2bf_rne(f1[1]);
            p[6] = f2bf_rne(f1[2]); p[7] = f2bf_rne(f1[3]);
            int q = q0 ^ (n & 7);
            *(short8*)&lsB[n * BK + q * 8] = p;
        }
        __syncthreads();

        // ---- compute: 2 MFMA K-substeps of 32 ----
        #pragma unroll
        for (int kk = 0; kk < 2; ++kk) {
            int kb = kk * 32 + quad * 8;
            int qs = kb >> 3;                   // chunk index of this frag
            short8 a[4], b[4];
            #pragma unroll
            for (int i = 0; i < 4; ++i) {
                int r = wm * 64 + i * 16 + lrow;
                a[i] = *(const short8*)&lsA[r * BK + ((qs ^ (r & 7)) * 8)];
            }
            #pragma unroll
            for (int j = 0; j < 4; ++j) {
                int n = wn * 64 + j * 16 + lrow;
                b[j] = *(const short8*)&lsB[n * BK + ((qs ^ (n & 7)) * 8)];
            }
            #pragma unroll
            for (int i = 0; i < 4; ++i)
                #pragma unroll
                for (int j = 0; j < 4; ++j)
                    acc[i][j] = __builtin_amdgcn_mfma_f32_16x16x32_bf16(
                        a[i], b[j], acc[i][j], 0, 0, 0);
        }
        __syncthreads();
    }

    // ---- epilogue: C/D layout col=lane&15, row=quad*4+reg; add bias ----
    #pragma unroll
    for (int j = 0; j < 4; ++j) {
        int gc = col0 + wn * 64 + j * 16 + lrow;   // global out column
        float bias = Bias[gc];                     // b is flat [4096]
        #pragma unroll
        for (int i = 0; i < 4; ++i) {
            int gr = row0 + wm * 64 + i * 16 + quad * 4;
            floatx4 v = acc[i][j];
            #pragma unroll
            for (int rg = 0; rg < 4; ++rg)
                Out[(size_t)(gr + rg) * OUT_F + gc] = v[rg] + bias;
        }
    }
}

extern "C" void kernel_launch(void* const* d_in, const int* in_sizes, int n_in,
                              void* d_out, int out_size, void* d_ws, size_t ws_size,
                              hipStream_t stream) {
    const float* X    = (const float*)d_in[0];   // [8192, 4096]
    const float* W    = (const float*)d_in[1];   // [16, 256, 256]
    const float* Bias = (const float*)d_in[2];   // [16, 256]
    float*       Out  = (float*)d_out;           // [8192, 4096]

    dim3 grid(64 * 32);   // 64 M-tiles x 32 N-tiles
    dim3 block(256);
    grouped_linear_kernel<<<grid, block, 0, stream>>>(X, W, Bias, Out);
}